// Round 3
// baseline (361.827 us; speedup 1.0000x reference)
//
#include <hip/hip_runtime.h>
#include <math.h>

// Problem shape (fixed by reference setup_inputs).
#define B_ 64
#define S_ 4096
#define D_ 256
#define SPLITS 32                       // S-splits per batch
#define ROWS_PER_BLOCK (S_ / SPLITS)    // 128
#define NWAVES 4                        // 256 threads / 64
#define ROWS_PER_WAVE (ROWS_PER_BLOCK / NWAVES)  // 32
#define NPART (B_ * SPLITS)             // 2048 partials

// Kernel 1: fused score + online-softmax + weighted accumulation.
// One block = (b, split) slice of 128 rows. Each wave streams 32 contiguous
// rows; lane l owns columns [4l, 4l+4) as float4 (coalesced 1 KiB per row).
// Score is reduced across the wave via shfl butterfly -> wave-uniform, so the
// online-max rescale branch is non-divergent. enc is read exactly once.
__global__ __launch_bounds__(256) void ta_partial(
    const float* __restrict__ enc, const float* __restrict__ We_w,
    const float* __restrict__ We_b, const float* __restrict__ ut_w,
    float* __restrict__ ws)
{
    const int blk   = blockIdx.x;
    const int b     = blk >> 5;             // / SPLITS
    const int split = blk & (SPLITS - 1);
    const int tid   = threadIdx.x;
    const int wave  = tid >> 6;
    const int lane  = tid & 63;

    const float4 w4  = reinterpret_cast<const float4*>(We_w)[lane];
    const float bias = We_b[0];
    const float ut   = ut_w[0];

    const float* rowbase = enc +
        ((size_t)b * S_ + (size_t)split * ROWS_PER_BLOCK +
         (size_t)wave * ROWS_PER_WAVE) * D_;

    float m = -INFINITY, l = 0.0f;
    float ax = 0.0f, ay = 0.0f, az = 0.0f, aw = 0.0f;

    #pragma unroll 2
    for (int r = 0; r < ROWS_PER_WAVE; ++r) {
        const float4 v =
            reinterpret_cast<const float4*>(rowbase + (size_t)r * D_)[lane];
        float dot = v.x * w4.x;
        dot = fmaf(v.y, w4.y, dot);
        dot = fmaf(v.z, w4.z, dot);
        dot = fmaf(v.w, w4.w, dot);
        // 64-lane butterfly: every lane ends with the full row dot.
        #pragma unroll
        for (int mask = 32; mask >= 1; mask >>= 1)
            dot += __shfl_xor(dot, mask, 64);
        const float s  = (dot + bias) * ut;
        const float mn = fmaxf(m, s);
        if (mn > m) {                       // wave-uniform branch
            const float c = __expf(m - mn); // exp(-inf)=0 handles first iter
            l *= c; ax *= c; ay *= c; az *= c; aw *= c;
            m = mn;
        }
        const float p = __expf(s - m);
        l += p;
        ax = fmaf(p, v.x, ax);
        ay = fmaf(p, v.y, ay);
        az = fmaf(p, v.z, az);
        aw = fmaf(p, v.w, aw);
    }

    // Merge 4 wave partials through LDS into one block partial.
    __shared__ float  sm[NWAVES], sl[NWAVES];
    __shared__ float4 sacc[NWAVES][64];
    sacc[wave][lane] = make_float4(ax, ay, az, aw);
    if (lane == 0) { sm[wave] = m; sl[wave] = l; }
    __syncthreads();

    const float M  = fmaxf(fmaxf(sm[0], sm[1]), fmaxf(sm[2], sm[3]));
    const float f0 = __expf(sm[0] - M), f1 = __expf(sm[1] - M);
    const float f2 = __expf(sm[2] - M), f3 = __expf(sm[3] - M);
    const float L  = f0 * sl[0] + f1 * sl[1] + f2 * sl[2] + f3 * sl[3];

    // Thread tid owns output column d = tid.
    const float* sa = reinterpret_cast<const float*>(&sacc[0][0]);
    const float av = f0 * sa[0 * D_ + tid] + f1 * sa[1 * D_ + tid] +
                     f2 * sa[2 * D_ + tid] + f3 * sa[3 * D_ + tid];

    float* ws_acc = ws;                                 // [NPART][D_]
    float* ws_m   = ws + (size_t)NPART * D_;            // [NPART]
    float* ws_l   = ws_m + NPART;                       // [NPART]
    ws_acc[(size_t)blk * D_ + tid] = av;
    if (tid == 0) { ws_m[blk] = M; ws_l[blk] = L; }
}

// Kernel 2: merge the 32 split-partials per batch, normalize, write [D, B].
__global__ __launch_bounds__(256) void ta_reduce(
    const float* __restrict__ ws, float* __restrict__ out)
{
    const int b = blockIdx.x;
    const int d = threadIdx.x;
    const float* ws_acc = ws;
    const float* ws_m   = ws + (size_t)NPART * D_;
    const float* ws_l   = ws_m + NPART;

    float M = -INFINITY;
    #pragma unroll
    for (int i = 0; i < SPLITS; ++i)
        M = fmaxf(M, ws_m[b * SPLITS + i]);

    float L = 0.0f, acc = 0.0f;
    #pragma unroll 4
    for (int i = 0; i < SPLITS; ++i) {
        const int p   = b * SPLITS + i;
        const float f = __expf(ws_m[p] - M);
        L   += f * ws_l[p];
        acc  = fmaf(f, ws_acc[(size_t)p * D_ + d], acc);
    }
    out[(size_t)d * B_ + b] = acc / L;   // out is [D, B] row-major
}

extern "C" void kernel_launch(void* const* d_in, const int* in_sizes, int n_in,
                              void* d_out, int out_size, void* d_ws, size_t ws_size,
                              hipStream_t stream)
{
    const float* enc  = (const float*)d_in[0];
    const float* We_w = (const float*)d_in[1];
    const float* We_b = (const float*)d_in[2];
    const float* ut_w = (const float*)d_in[3];
    float* out = (float*)d_out;
    float* ws  = (float*)d_ws;   // needs NPART*(D_+2)*4 ≈ 2.1 MB

    ta_partial<<<NPART, 256, 0, stream>>>(enc, We_w, We_b, ut_w, ws);
    ta_reduce<<<B_, 256, 0, stream>>>(ws, out);
}

// Round 4
// 360.926 us; speedup vs baseline: 1.0025x; 1.0025x over previous
//
#include <hip/hip_runtime.h>
#include <math.h>

// Problem shape (fixed by reference setup_inputs).
#define B_ 64
#define S_ 4096
#define D_ 256
#define SPLITS 32                       // S-splits per batch
#define ROWS_PER_BLOCK (S_ / SPLITS)    // 128
#define NWAVES 4                        // 256 threads / 64
#define ROWS_PER_WAVE (ROWS_PER_BLOCK / NWAVES)  // 32
#define NBATCH (ROWS_PER_WAVE / 8)      // 4 batches of 8 rows
#define NPART (B_ * SPLITS)             // 2048 partials

__device__ __forceinline__ float bcast(float x, int srcLane) {
    // wave-uniform broadcast via readlane (result lands in SGPR)
    return __int_as_float(__builtin_amdgcn_readlane(__float_as_int(x), srcLane));
}

// Kernel 1: fused score + online-softmax + weighted accumulation.
// 8 rows per step: 8 independent float4 loads (double-buffered -> 8 KiB in
// flight per wave), then a fold-reduction (10 shfls per 8 rows instead of
// 6 per row) and ONE branchless online-softmax update per batch.
__global__ __launch_bounds__(256) void ta_partial(
    const float* __restrict__ enc, const float* __restrict__ We_w,
    const float* __restrict__ We_b, const float* __restrict__ ut_w,
    float* __restrict__ ws)
{
    const int blk   = blockIdx.x;
    const int b     = blk >> 5;             // / SPLITS
    const int split = blk & (SPLITS - 1);
    const int tid   = threadIdx.x;
    const int wave  = tid >> 6;
    const int lane  = tid & 63;

    const float4 w4  = reinterpret_cast<const float4*>(We_w)[lane];
    const float bias = We_b[0];
    const float ut   = ut_w[0];

    const float* rowbase = enc +
        ((size_t)b * S_ + (size_t)split * ROWS_PER_BLOCK +
         (size_t)wave * ROWS_PER_WAVE) * D_;

    const bool h1 = lane & 1, h2 = lane & 2, h3 = lane & 4;
    // lane l (l&7 group) ends the fold holding the full dot of row
    // rowOfLane = 4*(l&1) + 2*((l>>1)&1) + ((l>>2)&1); inverse permutation:
    // row r lives in lane SRC[r] (bit-reverse of 3 bits, an involution).

    float m = -INFINITY, l = 0.0f;
    float ax = 0.0f, ay = 0.0f, az = 0.0f, aw = 0.0f;

    float4 buf[2][8];
    #pragma unroll
    for (int r = 0; r < 8; ++r)
        buf[0][r] = reinterpret_cast<const float4*>(rowbase + (size_t)r * D_)[lane];

    #pragma unroll
    for (int bt = 0; bt < NBATCH; ++bt) {
        const int cur = bt & 1, nxt = cur ^ 1;
        if (bt < NBATCH - 1) {
            #pragma unroll
            for (int r = 0; r < 8; ++r)
                buf[nxt][r] = reinterpret_cast<const float4*>(
                    rowbase + (size_t)((bt + 1) * 8 + r) * D_)[lane];
        }

        // per-lane partial dots for 8 rows
        float pd[8];
        #pragma unroll
        for (int r = 0; r < 8; ++r) {
            const float4 v = buf[cur][r];
            float d = v.x * w4.x;
            d = fmaf(v.y, w4.y, d);
            d = fmaf(v.z, w4.z, d);
            d = fmaf(v.w, w4.w, d);
            pd[r] = d;
        }

        // fold 8 -> 4 -> 2 -> 1 (value-halving exchanges), then 3 butterflies
        float q[4];
        #pragma unroll
        for (int k = 0; k < 4; ++k) {
            const float send = h1 ? pd[k] : pd[k + 4];
            const float keep = h1 ? pd[k + 4] : pd[k];
            q[k] = keep + __shfl_xor(send, 1, 64);
        }
        float u[2];
        #pragma unroll
        for (int k = 0; k < 2; ++k) {
            const float send = h2 ? q[k] : q[k + 2];
            const float keep = h2 ? q[k + 2] : q[k];
            u[k] = keep + __shfl_xor(send, 2, 64);
        }
        float t;
        {
            const float send = h3 ? u[0] : u[1];
            const float keep = h3 ? u[1] : u[0];
            t = keep + __shfl_xor(send, 4, 64);
        }
        t += __shfl_xor(t, 8, 64);
        t += __shfl_xor(t, 16, 64);
        t += __shfl_xor(t, 32, 64);

        // broadcast the 8 row-scores to all lanes (SGPR-uniform)
        float s[8];
        s[0] = (bcast(t, 0) + bias) * ut;
        s[1] = (bcast(t, 4) + bias) * ut;
        s[2] = (bcast(t, 2) + bias) * ut;
        s[3] = (bcast(t, 6) + bias) * ut;
        s[4] = (bcast(t, 1) + bias) * ut;
        s[5] = (bcast(t, 5) + bias) * ut;
        s[6] = (bcast(t, 3) + bias) * ut;
        s[7] = (bcast(t, 7) + bias) * ut;

        // one branchless online-softmax update per 8-row batch
        float pm = s[0];
        #pragma unroll
        for (int r = 1; r < 8; ++r) pm = fmaxf(pm, s[r]);
        const float mn = fmaxf(m, pm);
        const float c  = __expf(m - mn);     // exp(-inf)=0 handles first batch
        m = mn;
        l *= c; ax *= c; ay *= c; az *= c; aw *= c;

        #pragma unroll
        for (int r = 0; r < 8; ++r) {
            const float p = __expf(s[r] - mn);
            const float4 v = buf[cur][r];
            l  += p;
            ax  = fmaf(p, v.x, ax);
            ay  = fmaf(p, v.y, ay);
            az  = fmaf(p, v.z, az);
            aw  = fmaf(p, v.w, aw);
        }
    }

    // Merge 4 wave partials through LDS into one block partial.
    __shared__ float  sm[NWAVES], sl[NWAVES];
    __shared__ float4 sacc[NWAVES][64];
    sacc[wave][lane] = make_float4(ax, ay, az, aw);
    if (lane == 0) { sm[wave] = m; sl[wave] = l; }
    __syncthreads();

    const float M  = fmaxf(fmaxf(sm[0], sm[1]), fmaxf(sm[2], sm[3]));
    const float f0 = __expf(sm[0] - M), f1 = __expf(sm[1] - M);
    const float f2 = __expf(sm[2] - M), f3 = __expf(sm[3] - M);
    const float L  = f0 * sl[0] + f1 * sl[1] + f2 * sl[2] + f3 * sl[3];

    // Thread tid owns output column d = tid.
    const float* sa = reinterpret_cast<const float*>(&sacc[0][0]);
    const float av = f0 * sa[0 * D_ + tid] + f1 * sa[1 * D_ + tid] +
                     f2 * sa[2 * D_ + tid] + f3 * sa[3 * D_ + tid];

    float* ws_acc = ws;                                 // [NPART][D_]
    float* ws_m   = ws + (size_t)NPART * D_;            // [NPART]
    float* ws_l   = ws_m + NPART;                       // [NPART]
    ws_acc[(size_t)blk * D_ + tid] = av;
    if (tid == 0) { ws_m[blk] = M; ws_l[blk] = L; }
}

// Kernel 2: merge the 32 split-partials per batch, normalize, write [D, B].
__global__ __launch_bounds__(256) void ta_reduce(
    const float* __restrict__ ws, float* __restrict__ out)
{
    const int b = blockIdx.x;
    const int d = threadIdx.x;
    const float* ws_acc = ws;
    const float* ws_m   = ws + (size_t)NPART * D_;
    const float* ws_l   = ws_m + NPART;

    float M = -INFINITY;
    #pragma unroll
    for (int i = 0; i < SPLITS; ++i)
        M = fmaxf(M, ws_m[b * SPLITS + i]);

    float L = 0.0f, acc = 0.0f;
    #pragma unroll 4
    for (int i = 0; i < SPLITS; ++i) {
        const int p   = b * SPLITS + i;
        const float f = __expf(ws_m[p] - M);
        L   += f * ws_l[p];
        acc  = fmaf(f, ws_acc[(size_t)p * D_ + d], acc);
    }
    out[(size_t)d * B_ + b] = acc / L;   // out is [D, B] row-major
}

extern "C" void kernel_launch(void* const* d_in, const int* in_sizes, int n_in,
                              void* d_out, int out_size, void* d_ws, size_t ws_size,
                              hipStream_t stream)
{
    const float* enc  = (const float*)d_in[0];
    const float* We_w = (const float*)d_in[1];
    const float* We_b = (const float*)d_in[2];
    const float* ut_w = (const float*)d_in[3];
    float* out = (float*)d_out;
    float* ws  = (float*)d_ws;   // needs NPART*(D_+2)*4 ≈ 2.1 MB

    ta_partial<<<NPART, 256, 0, stream>>>(enc, We_w, We_b, ut_w, ws);
    ta_reduce<<<B_, 256, 0, stream>>>(ws, out);
}